// Round 8
// baseline (637.827 us; speedup 1.0000x reference)
//
#include <hip/hip_runtime.h>

// RWKV v7 TimeMix forward, MI355X gfx950.
// B=8 T=2048 C=1024 H=16 D=64 DLOW=64. I/O f32, internal bf16 MFMA + f32 scan.
// R8: R6 grid ordering restored (m-tile fastest); stage1 merged into rkv launch
//     (dispatched first, hides under rkv MFMA); scan1 joint butterfly + bf16
//     state buffer. 5 launches.

typedef __bf16 bf16;
typedef __attribute__((ext_vector_type(8))) __bf16 bf16x8;
typedef __attribute__((ext_vector_type(4))) float f32x4;

#define TBTOK 16384   // B*T
#define TSEQ  2048
#define CDIM  1024
#define HN    16
#define CHUNK 32
#define NCH   64      // TSEQ / CHUNK

__device__ __forceinline__ float redsum8(float v) {  // 8 consecutive lanes
#pragma unroll
  for (int o = 4; o > 0; o >>= 1) v += __shfl_xor(v, o, 64);
  return v;
}
__device__ __forceinline__ float sigmf(float x) { return 1.f / (1.f + expf(-x)); }

// async global->LDS, 16 bytes/lane. LDS base wave-uniform (HW adds lane*16).
__device__ __forceinline__ void gl_lds16(const bf16* g, bf16* l) {
  __builtin_amdgcn_global_load_lds(
      (const __attribute__((address_space(1))) unsigned int*)g,
      (__attribute__((address_space(3))) unsigned int*)l, 16, 0, 0);
}

// ---------------- prep: mixcvt (blocks 0..8191) + all weight transposes ----------
__global__ __launch_bounds__(256) void prep_kern(
    const float* __restrict__ x, const float* __restrict__ mr,
    const float* __restrict__ mk, const float* __restrict__ mv,
    bf16* __restrict__ xr, bf16* __restrict__ xk, bf16* __restrict__ xv,
    bf16* __restrict__ xbf,
    const float* __restrict__ Wr, const float* __restrict__ Wk,
    const float* __restrict__ Wv, const float* __restrict__ Wo,
    const float* __restrict__ w1, const float* __restrict__ a1, const float* __restrict__ g1,
    const float* __restrict__ mw, const float* __restrict__ ma, const float* __restrict__ mg,
    const float* __restrict__ g2, const float* __restrict__ w2, const float* __restrict__ a2,
    bf16* __restrict__ WrT, bf16* __restrict__ WkT, bf16* __restrict__ WvT, bf16* __restrict__ WoT,
    bf16* __restrict__ Bcat, bf16* __restrict__ g2T,
    bf16* __restrict__ w2T, bf16* __restrict__ a2T, float* __restrict__ zpad) {
  int bid0 = blockIdx.x;
  int tid = threadIdx.x;
  if (bid0 < 8192) {
    long i8 = ((long)bid0 * 256 + tid) * 8;
    int m = (int)(i8 >> 10);
    int c = (int)(i8 & 1023);
    f32x4 x0 = *(const f32x4*)(x + i8);
    f32x4 x1 = *(const f32x4*)(x + i8 + 4);
    f32x4 p0 = {0.f, 0.f, 0.f, 0.f}, p1 = {0.f, 0.f, 0.f, 0.f};
    if ((m & (TSEQ - 1)) != 0) {
      p0 = *(const f32x4*)(x + i8 - CDIM);
      p1 = *(const f32x4*)(x + i8 - CDIM + 4);
    }
    f32x4 r0 = *(const f32x4*)(mr + c), r1 = *(const f32x4*)(mr + c + 4);
    f32x4 k0 = *(const f32x4*)(mk + c), k1 = *(const f32x4*)(mk + c + 4);
    f32x4 v0 = *(const f32x4*)(mv + c), v1 = *(const f32x4*)(mv + c + 4);
    bf16x8 or_, ok_, ov_, ox_;
#pragma unroll
    for (int j = 0; j < 4; j++) {
      float s0 = x0[j] - p0[j], s1 = x1[j] - p1[j];
      or_[j] = (bf16)(x0[j] + s0 * r0[j]); or_[4 + j] = (bf16)(x1[j] + s1 * r1[j]);
      ok_[j] = (bf16)(x0[j] + s0 * k0[j]); ok_[4 + j] = (bf16)(x1[j] + s1 * k1[j]);
      ov_[j] = (bf16)(x0[j] + s0 * v0[j]); ov_[4 + j] = (bf16)(x1[j] + s1 * v1[j]);
      ox_[j] = (bf16)x0[j];                ox_[4 + j] = (bf16)x1[j];
    }
    *(bf16x8*)(xr + i8) = or_;
    *(bf16x8*)(xk + i8) = ok_;
    *(bf16x8*)(xv + i8) = ov_;
    *(bf16x8*)(xbf + i8) = ox_;
    return;
  }
  int bid = bid0 - 8192;
  int tx = tid & 31, ty = tid >> 5;  // 32 x 8
  __shared__ bf16 tile[32][33];
  if (bid < 4096) {
    int sel = bid >> 10, t = bid & 1023;
    int k0 = (t >> 5) * 32, n0 = (t & 31) * 32;
    const float* src = sel == 0 ? Wr : (sel == 1 ? Wk : (sel == 2 ? Wv : Wo));
    bf16* dst = sel == 0 ? WrT : (sel == 1 ? WkT : (sel == 2 ? WvT : WoT));
#pragma unroll
    for (int i = 0; i < 4; i++)
      tile[ty + i * 8][tx] = (bf16)src[(long)(k0 + ty + i * 8) * 1024 + n0 + tx];
    __syncthreads();
#pragma unroll
    for (int i = 0; i < 4; i++)
      dst[(long)(n0 + ty + i * 8) * 1024 + k0 + tx] = tile[tx][ty + i * 8];
  } else if (bid < 4480) {
    int idx = bid - 4096;
    int mat = idx >> 7, rem = idx & 127;
    int half = rem >> 6, t = rem & 63;
    int k0 = (t >> 1) * 32, n0 = (t & 1) * 32;
    const float* W = mat == 0 ? w1 : (mat == 1 ? a1 : g1);
    const float* mx = mat == 0 ? mw : (mat == 1 ? ma : mg);
#pragma unroll
    for (int i = 0; i < 4; i++) {
      int k = k0 + ty + i * 8;
      float s = half == 0 ? (1.f + mx[k]) : (-mx[k]);
      tile[ty + i * 8][tx] = (bf16)(s * W[(long)k * 64 + n0 + tx]);
    }
    __syncthreads();
#pragma unroll
    for (int i = 0; i < 4; i++)
      Bcat[(long)(mat * 64 + n0 + ty + i * 8) * 2048 + half * 1024 + k0 + tx] =
          tile[tx][ty + i * 8];
  } else if (bid < 4544) {
    int t = bid - 4480;
    int k0 = (t >> 5) * 32, n0 = (t & 31) * 32;
#pragma unroll
    for (int i = 0; i < 4; i++)
      tile[ty + i * 8][tx] = (bf16)g2[(long)(k0 + ty + i * 8) * 1024 + n0 + tx];
    __syncthreads();
#pragma unroll
    for (int i = 0; i < 4; i++)
      g2T[(long)(n0 + ty + i * 8) * 64 + k0 + tx] = tile[tx][ty + i * 8];
  } else {
#pragma unroll
    for (int rep = 0; rep < 4; rep++) {
      int idx = rep * 256 + tid;  // 0..1023
      int k = idx >> 4, h = idx & 15;
      w2T[h * 64 + k] = (bf16)w2[idx];
      a2T[h * 64 + k] = (bf16)a2[idx];
    }
    if (tid < 64) zpad[tid] = 0.f;
  }
}

// ---------------- merged rkv GEMM + LoRA stage1 ----------------
// grid (128, 28): y 0..3 = stage1 (dispatched first, latency-bound, hides under
// rkv); y 4..27 = rkv 128x128 tiles (mat=(y-4)/8, ncol=((y-4)%8)*128).
__global__ __launch_bounds__(256) void rkv_stage1_kern(
    const bf16* __restrict__ xr, const bf16* __restrict__ xk, const bf16* __restrict__ xv,
    const bf16* __restrict__ WrT, const bf16* __restrict__ WkT, const bf16* __restrict__ WvT,
    bf16* __restrict__ r_buf, bf16* __restrict__ k_buf, bf16* __restrict__ v_buf,
    const bf16* __restrict__ xbf, const bf16* __restrict__ Bcat,
    const float* __restrict__ zpad, const bf16* __restrict__ w2T, const bf16* __restrict__ a2T,
    const float* __restrict__ w0, const float* __restrict__ a0,
    bf16* __restrict__ t1g, float* __restrict__ w_arr, float* __restrict__ a_arr) {
  __shared__ __align__(16) char smem[32768];
  int tid = threadIdx.x;
  int w = tid >> 6, lane = tid & 63, quad = lane >> 4, lr = lane & 15;
  int y = blockIdx.y;

  if (y >= 4) {
    // ---------------- rkv path: 128x128, BK=64, XOR swizzle ----------------
    int yy = y - 4;
    int mat = yy >> 3;
    int ncol0 = (yy & 7) * 128;
    const bf16* Am = mat == 0 ? xr : (mat == 1 ? xk : xv);
    const bf16* BTm = mat == 0 ? WrT : (mat == 1 ? WkT : WvT);
    bf16* out = mat == 0 ? r_buf : (mat == 1 ? k_buf : v_buf);
    int m0 = blockIdx.x * 128;
    bf16* Al = (bf16*)smem;            // 16 KB
    bf16* Bl = (bf16*)(smem + 16384);  // 16 KB
    int wm = (w & 1) * 64, wn = (w >> 1) * 64;
    f32x4 acc[4][4] = {};
    int r0 = tid >> 3;
    int slot = tid & 7;
    int kg = (slot ^ (r0 & 7)) * 8;
    const bf16* ag = Am + (long)(m0 + r0) * CDIM + kg;
    const bf16* bg = BTm + (long)(ncol0 + r0) * 1024 + kg;
    long astep = (long)32 * CDIM;
    long bstep = (long)32 * 1024;
    bf16* la = Al + w * 512;
    bf16* lb = Bl + w * 512;
    for (int k0 = 0; k0 < 1024; k0 += 64) {
#pragma unroll
      for (int s = 0; s < 4; s++) gl_lds16(ag + s * astep, la + s * 2048);
#pragma unroll
      for (int s = 0; s < 4; s++) gl_lds16(bg + s * bstep, lb + s * 2048);
      ag += 64; bg += 64;
      __syncthreads();
#pragma unroll
      for (int ko = 0; ko < 2; ko++) {
        bf16x8 af[4], bff[4];
#pragma unroll
        for (int i = 0; i < 4; i++) {
          int ra = wm + i * 16 + lr;
          af[i] = *(const bf16x8*)&Al[ra * 64 + (((ko * 4 + quad) ^ (ra & 7)) * 8)];
        }
#pragma unroll
        for (int j = 0; j < 4; j++) {
          int rb = wn + j * 16 + lr;
          bff[j] = *(const bf16x8*)&Bl[rb * 64 + (((ko * 4 + quad) ^ (rb & 7)) * 8)];
        }
#pragma unroll
        for (int i = 0; i < 4; i++)
#pragma unroll
          for (int j = 0; j < 4; j++)
            acc[i][j] = __builtin_amdgcn_mfma_f32_16x16x32_bf16(af[i], bff[j], acc[i][j], 0, 0, 0);
      }
      __syncthreads();
    }
#pragma unroll
    for (int i = 0; i < 4; i++)
#pragma unroll
      for (int j = 0; j < 4; j++)
#pragma unroll
        for (int rg = 0; rg < 4; rg++) {
          int row = m0 + wm + i * 16 + quad * 4 + rg;
          int col = ncol0 + wn + j * 16 + lr;
          out[(long)row * CDIM + col] = (bf16)acc[i][j][rg];
        }
    return;
  }

  // ---------------- stage1 path: [x|xprev]@Bcat^T, 64-row tiles ----------------
  int part = y >> 1;             // 0: w+a cols, 1: g cols
  int m0 = blockIdx.x * 128 + (y & 1) * 64;
  bf16* Al = (bf16*)smem;             // 4 KB
  bf16* Bl = (bf16*)(smem + 4096);    // 8 KB
  bf16* Lt1 = (bf16*)(smem + 12288);  // 17 KB (part0)
  int wm = w * 16;
  int r0 = tid >> 2, kc0 = (tid & 3) * 8;
  int m = m0 + r0;
  const bf16* asrc = xbf + (long)m * CDIM + kc0;
  bool firstrow = (m & (TSEQ - 1)) == 0;
  const bf16* psrc = firstrow ? (const bf16*)zpad : xbf + (long)(m - 1) * CDIM + kc0;
  int pstep = firstrow ? 0 : 32;
  int brow0 = part ? 128 : 0;
  const bf16* bs0 = Bcat + (long)(brow0 + r0) * 2048 + kc0;
  const bf16* bs1 = bs0 + (long)64 * 2048;
  bf16* la = Al + w * 512;
  bf16* lb0 = Bl + w * 512;
  bf16* lb1 = Bl + 2048 + w * 512;

  if (part == 0) {
    f32x4 acc[8] = {};
#pragma unroll 1
    for (int kk = 0; kk < 64; kk++) {
      if (kk < 32) { gl_lds16(asrc, la); asrc += 32; }
      else         { gl_lds16(psrc, la); psrc += pstep; }
      gl_lds16(bs0, lb0);
      gl_lds16(bs1, lb1);
      bs0 += 32; bs1 += 32;
      __syncthreads();
      bf16x8 af = *(const bf16x8*)&Al[(wm + lr) * 32 + quad * 8];
#pragma unroll
      for (int nf = 0; nf < 8; nf++) {
        bf16x8 bff = *(const bf16x8*)&Bl[(nf * 16 + lr) * 32 + quad * 8];
        acc[nf] = __builtin_amdgcn_mfma_f32_16x16x32_bf16(af, bff, acc[nf], 0, 0, 0);
      }
      __syncthreads();
    }
#pragma unroll
    for (int nf = 0; nf < 8; nf++)
#pragma unroll
      for (int rg = 0; rg < 4; rg++) {
        int row = wm + quad * 4 + rg;
        Lt1[row * 136 + nf * 16 + lr] = (bf16)tanhf(acc[nf][rg]);
      }
    __syncthreads();
#pragma unroll
    for (int rep = 0; rep < 4; rep++) {
      int idx = rep * 256 + tid;
      int row = idx >> 4, h = idx & 15;
      const bf16* rw = &Lt1[row * 136];
      const bf16* ra = rw + 64;
      const bf16* ww = w2T + h * 64;
      const bf16* aw = a2T + h * 64;
      float dw = 0.f, da = 0.f;
#pragma unroll
      for (int k = 0; k < 64; k++) {
        dw += (float)rw[k] * (float)ww[k];
        da += (float)ra[k] * (float)aw[k];
      }
      w_arr[h * TBTOK + m0 + row] = 0.60653066f * sigmf(w0[h] + dw);
      a_arr[h * TBTOK + m0 + row] = sigmf(a0[h] + da);
    }
  } else {
    f32x4 acc[4] = {};
#pragma unroll 1
    for (int kk = 0; kk < 64; kk++) {
      if (kk < 32) { gl_lds16(asrc, la); asrc += 32; }
      else         { gl_lds16(psrc, la); psrc += pstep; }
      gl_lds16(bs0, lb0);
      bs0 += 32;
      __syncthreads();
      bf16x8 af = *(const bf16x8*)&Al[(wm + lr) * 32 + quad * 8];
#pragma unroll
      for (int nf = 0; nf < 4; nf++) {
        bf16x8 bff = *(const bf16x8*)&Bl[(nf * 16 + lr) * 32 + quad * 8];
        acc[nf] = __builtin_amdgcn_mfma_f32_16x16x32_bf16(af, bff, acc[nf], 0, 0, 0);
      }
      __syncthreads();
    }
#pragma unroll
    for (int nf = 0; nf < 4; nf++)
#pragma unroll
      for (int rg = 0; rg < 4; rg++) {
        int row = wm + quad * 4 + rg;
        t1g[(long)(m0 + row) * 64 + nf * 16 + lr] = (bf16)tanhf(acc[nf][rg]);
      }
  }
}

// ---------------- Wo GEMM: 128x128 tile, BK=64, XOR-swizzled LDS ----------------
__global__ __launch_bounds__(256) void gemm_wo_kern(
    const bf16* __restrict__ A, const bf16* __restrict__ BT, float* __restrict__ out) {
  int ncol0 = blockIdx.y * 128;
  int m0 = blockIdx.x * 128;
  __shared__ bf16 Al[128 * 64];
  __shared__ bf16 Bl[128 * 64];
  int tid = threadIdx.x;
  int w = tid >> 6, lane = tid & 63, quad = lane >> 4, lr = lane & 15;
  int wm = (w & 1) * 64, wn = (w >> 1) * 64;
  f32x4 acc[4][4] = {};
  int r0 = tid >> 3;
  int slot = tid & 7;
  int kg = (slot ^ (r0 & 7)) * 8;
  const bf16* ag = A + (long)(m0 + r0) * CDIM + kg;
  const bf16* bg = BT + (long)(ncol0 + r0) * 1024 + kg;
  long astep = (long)32 * CDIM;
  long bstep = (long)32 * 1024;
  bf16* la = Al + w * 512;
  bf16* lb = Bl + w * 512;
  for (int k0 = 0; k0 < 1024; k0 += 64) {
#pragma unroll
    for (int s = 0; s < 4; s++) gl_lds16(ag + s * astep, la + s * 2048);
#pragma unroll
    for (int s = 0; s < 4; s++) gl_lds16(bg + s * bstep, lb + s * 2048);
    ag += 64; bg += 64;
    __syncthreads();
#pragma unroll
    for (int ko = 0; ko < 2; ko++) {
      bf16x8 af[4], bff[4];
#pragma unroll
      for (int i = 0; i < 4; i++) {
        int ra = wm + i * 16 + lr;
        af[i] = *(const bf16x8*)&Al[ra * 64 + (((ko * 4 + quad) ^ (ra & 7)) * 8)];
      }
#pragma unroll
      for (int j = 0; j < 4; j++) {
        int rb = wn + j * 16 + lr;
        bff[j] = *(const bf16x8*)&Bl[rb * 64 + (((ko * 4 + quad) ^ (rb & 7)) * 8)];
      }
#pragma unroll
      for (int i = 0; i < 4; i++)
#pragma unroll
        for (int j = 0; j < 4; j++)
          acc[i][j] = __builtin_amdgcn_mfma_f32_16x16x32_bf16(af[i], bff[j], acc[i][j], 0, 0, 0);
    }
    __syncthreads();
  }
#pragma unroll
  for (int i = 0; i < 4; i++)
#pragma unroll
    for (int j = 0; j < 4; j++)
#pragma unroll
      for (int rg = 0; rg < 4; rg++) {
        int row = m0 + wm + i * 16 + quad * 4 + rg;
        int col = ncol0 + wn + j * 16 + lr;
        out[(long)row * CDIM + col] = acc[i][j][rg];
      }
}

// ---------------- scan1: fused prep + local 32-token scan (joint butterfly) -------
__global__ __launch_bounds__(256) void scan1_kern(
    const bf16* __restrict__ k_buf, const bf16* __restrict__ v_buf, const bf16* __restrict__ r_buf,
    const float* __restrict__ k_k, const float* __restrict__ r_k,
    const float* __restrict__ a_arr, const float* __restrict__ w_arr,
    bf16* __restrict__ kv2b, float* __restrict__ Parr, float* __restrict__ bonus,
    float* __restrict__ Lend) {
  int wid = blockIdx.x * 4 + (threadIdx.x >> 6);
  int lane = threadIdx.x & 63;
  int bh = wid >> 6, c = wid & 63;
  int b = bh >> 4, h = bh & 15;
  int mstart = b * TSEQ + c * CHUNK;
  int kc = h * 64 + lane;
  float kkc = k_k[kc], rkc = r_k[kc];
  float st = 0.f, cw = 1.f;
  long mbase = (long)mstart * CDIM + kc;
  int hm = h * TBTOK + mstart;
  long sbase = ((long)hm) * 64 + lane;
  float kf = (float)k_buf[mbase] * kkc;
  float vf = (float)v_buf[mbase];
  float rf = (float)r_buf[mbase];
  float af = a_arr[hm];
  float wt = w_arr[hm];
  for (int t = 0; t < CHUNK; t++) {
    float kf_n = 0.f, vf_n = 0.f, rf_n = 0.f, af_n = 0.f, wt_n = 0.f;
    if (t < CHUNK - 1) {
      kf_n = (float)k_buf[mbase + CDIM] * kkc;
      vf_n = (float)v_buf[mbase + CDIM];
      rf_n = (float)r_buf[mbase + CDIM];
      af_n = a_arr[hm + 1];
      wt_n = w_arr[hm + 1];
    }
    // joint butterfly: ss = sum kf^2 ; bb = sum rf*rkc*kf  (independent -> ILP 2)
    float ss = kf * kf;
    float bb = rf * rkc * kf;
#pragma unroll
    for (int o = 32; o > 0; o >>= 1) {
      ss += __shfl_xor(ss, o, 64);
      bb += __shfl_xor(bb, o, 64);
    }
    float denom = fmaxf(sqrtf(ss), 1e-12f);
    float kkn = kf / denom;
    st = st * wt + kkn * vf * af;
    kv2b[sbase] = (bf16)st;
    cw *= wt;
    if (lane == 0) {
      Parr[hm] = cw;
      bonus[(mstart + t) * HN + h] = bb / denom;
    }
    kf = kf_n; vf = vf_n; rf = rf_n; af = af_n; wt = wt_n;
    mbase += CDIM; hm += 1; sbase += 64;
  }
  // carry entering next chunk == this chunk's final state (P_chunk <= e^-16)
  Lend[(long)wid * 64 + lane] = st;
}

// ---------------- gate_post: g=sigmoid(t1g@g2) -> LDS; vectorized fixup+groupnorm ----
__global__ __launch_bounds__(256) void gate_post_kern(
    const bf16* __restrict__ t1g, const bf16* __restrict__ g2T,
    const bf16* __restrict__ kv2b, const float* __restrict__ Parr,
    const float* __restrict__ Lend, const float* __restrict__ bonus,
    bf16* __restrict__ r_buf, const bf16* __restrict__ v_buf,
    const float* __restrict__ ln_w, const float* __restrict__ ln_b) {
  int ncol0 = blockIdx.x * 128;
  int m0 = blockIdx.y * 128;

  __shared__ bf16 Al[128 * 32];       // 8 KB
  __shared__ bf16 Bl[128 * 32];       // 8 KB
  __shared__ bf16 gtile[128 * 136];   // 34 KB

  int tid = threadIdx.x;
  int w = tid >> 6, lane = tid & 63, quad = lane >> 4, lr = lane & 15;
  int wm = (w & 1) * 64, wn = (w >> 1) * 64;

  f32x4 acc[4][4] = {};

  int r0 = tid >> 2, kc0 = (tid & 3) * 8;
  const bf16* ag0 = t1g + (long)(m0 + r0) * 64 + kc0;
  const bf16* ag1 = ag0 + (long)64 * 64;
  const bf16* bg0 = g2T + (long)(ncol0 + r0) * 64 + kc0;
  const bf16* bg1 = bg0 + (long)64 * 64;
  bf16* la0 = Al + w * 512;
  bf16* la1 = Al + 2048 + w * 512;
  bf16* lb0 = Bl + w * 512;
  bf16* lb1 = Bl + 2048 + w * 512;

  for (int k0 = 0; k0 < 64; k0 += 32) {
    gl_lds16(ag0, la0);
    gl_lds16(ag1, la1);
    gl_lds16(bg0, lb0);
    gl_lds16(bg1, lb1);
    ag0 += 32; ag1 += 32; bg0 += 32; bg1 += 32;
    __syncthreads();
    bf16x8 af[4], bff[4];
#pragma unroll
    for (int i = 0; i < 4; i++) af[i] = *(const bf16x8*)&Al[(wm + i * 16 + lr) * 32 + quad * 8];
#pragma unroll
    for (int j = 0; j < 4; j++) bff[j] = *(const bf16x8*)&Bl[(wn + j * 16 + lr) * 32 + quad * 8];
#pragma unroll
    for (int i = 0; i < 4; i++)
#pragma unroll
      for (int j = 0; j < 4; j++)
        acc[i][j] = __builtin_amdgcn_mfma_f32_16x16x32_bf16(af[i], bff[j], acc[i][j], 0, 0, 0);
    __syncthreads();
  }
#pragma unroll
  for (int i = 0; i < 4; i++)
#pragma unroll
    for (int j = 0; j < 4; j++)
#pragma unroll
      for (int rg = 0; rg < 4; rg++) {
        int row = wm + i * 16 + quad * 4 + rg;
        int col = wn + j * 16 + lr;
        gtile[row * 136 + col] = (bf16)sigmf(acc[i][j][rg]);
      }
  __syncthreads();

  // phase 2: 8 contiguous channels per thread; fully vectorized global access
  int c_loc = (tid & 15) * 8;            // 0..120
  int col_g = ncol0 + c_loc;
  int h = col_g >> 6;
  int d0 = col_g & 63;
  f32x4 lnw0 = *(const f32x4*)(ln_w + col_g);
  f32x4 lnw1 = *(const f32x4*)(ln_w + col_g + 4);
  f32x4 lnb0 = *(const f32x4*)(ln_b + col_g);
  f32x4 lnb1 = *(const f32x4*)(ln_b + col_g + 4);
#pragma unroll
  for (int jj = 0; jj < 8; jj++) {
    int row = jj * 16 + (tid >> 4);
    int row_g = m0 + row;
    int b = row_g >> 11;
    int ch = (row_g & (TSEQ - 1)) >> 5;
    long kvb = ((long)h * TBTOK + row_g) * 64 + d0;
    bf16x8 st8 = *(const bf16x8*)(kv2b + kvb);
    f32x4 cy0 = {0.f, 0.f, 0.f, 0.f}, cy1 = {0.f, 0.f, 0.f, 0.f};
    if (ch != 0) {
      long lb = ((long)((b * 16 + h) * NCH + ch - 1)) * 64 + d0;
      cy0 = *(const f32x4*)(Lend + lb);
      cy1 = *(const f32x4*)(Lend + lb + 4);
    }
    float pw = Parr[h * TBTOK + row_g];
    float bs = bonus[row_g * HN + h];
    long rb = (long)row_g * CDIM + col_g;
    bf16x8 rf8 = *(const bf16x8*)(r_buf + rb);
    bf16x8 vf8 = *(const bf16x8*)(v_buf + rb);
    bf16x8 g8 = *(const bf16x8*)&gtile[row * 136 + c_loc];
    float xw[8];
#pragma unroll
    for (int q = 0; q < 4; q++) {
      xw[q]     = ((float)st8[q] + pw * cy0[q]) * (float)rf8[q]     + bs * (float)vf8[q];
      xw[4 + q] = ((float)st8[4 + q] + pw * cy1[q]) * (float)rf8[4 + q] + bs * (float)vf8[4 + q];
    }
    float sum = 0.f;
#pragma unroll
    for (int q = 0; q < 8; q++) sum += xw[q];
    float mn = redsum8(sum) * (1.f / 64.f);
    float vs = 0.f;
#pragma unroll
    for (int q = 0; q < 8; q++) {
      xw[q] -= mn;
      vs += xw[q] * xw[q];
    }
    float var = redsum8(vs) * (1.f / 64.f);
    float rq = rsqrtf(var + 1e-5f);
    bf16x8 o8;
#pragma unroll
    for (int q = 0; q < 4; q++) {
      o8[q]     = (bf16)((xw[q] * rq * lnw0[q] + lnb0[q]) * (float)g8[q]);
      o8[4 + q] = (bf16)((xw[4 + q] * rq * lnw1[q] + lnb1[q]) * (float)g8[4 + q]);
    }
    *(bf16x8*)(r_buf + rb) = o8;
  }
}

extern "C" void kernel_launch(void* const* d_in, const int* in_sizes, int n_in,
                              void* d_out, int out_size, void* d_ws, size_t ws_size,
                              hipStream_t stream) {
  const float* x    = (const float*)d_in[0];
  const float* x_r  = (const float*)d_in[1];
  const float* x_w  = (const float*)d_in[2];
  const float* x_k  = (const float*)d_in[3];
  const float* x_v  = (const float*)d_in[4];
  const float* x_a  = (const float*)d_in[5];
  const float* x_g  = (const float*)d_in[6];
  const float* w0   = (const float*)d_in[7];
  const float* w1   = (const float*)d_in[8];
  const float* w2   = (const float*)d_in[9];
  const float* a0   = (const float*)d_in[10];
  const float* a1   = (const float*)d_in[11];
  const float* a2   = (const float*)d_in[12];
  // v0,v1,v2 (13,14,15) unused: v_res_gate is a no-op in the reference
  const float* g1   = (const float*)d_in[16];
  const float* g2   = (const float*)d_in[17];
  const float* k_k  = (const float*)d_in[18];
  const float* r_k  = (const float*)d_in[19];
  const float* Wr   = (const float*)d_in[20];
  const float* Wk   = (const float*)d_in[21];
  const float* Wv   = (const float*)d_in[22];
  const float* Wo   = (const float*)d_in[23];
  const float* ln_w = (const float*)d_in[24];
  const float* ln_b = (const float*)d_in[25];
  float* out = (float*)d_out;

  char* p = (char*)d_ws;
  auto carve = [&](size_t bytes) {
    void* r = (void*)p;
    p += (bytes + 255) & ~(size_t)255;
    return r;
  };
  bf16* WrT = (bf16*)carve(1024 * 1024 * 2);
  bf16* WkT = (bf16*)carve(1024 * 1024 * 2);
  bf16* WvT = (bf16*)carve(1024 * 1024 * 2);
  bf16* WoT = (bf16*)carve(1024 * 1024 * 2);
  bf16* Bcat = (bf16*)carve(192 * 2048 * 2);
  bf16* g2T  = (bf16*)carve(1024 * 64 * 2);
  bf16* w2T  = (bf16*)carve(16 * 64 * 2);
  bf16* a2T  = (bf16*)carve(16 * 64 * 2);
  float* zpad = (float*)carve(64 * 4);
  bf16* t1g   = (bf16*)carve((size_t)TBTOK * 64 * 2);
  bf16* r_buf = (bf16*)carve((size_t)TBTOK * CDIM * 2);
  bf16* k_buf = (bf16*)carve((size_t)TBTOK * CDIM * 2);
  bf16* v_buf = (bf16*)carve((size_t)TBTOK * CDIM * 2);
  float* w_arr = (float*)carve((size_t)TBTOK * HN * 4);
  float* a_arr = (float*)carve((size_t)TBTOK * HN * 4);
  float* bonus = (float*)carve((size_t)TBTOK * HN * 4);
  float* Parr  = (float*)carve((size_t)TBTOK * HN * 4);
  float* Lend  = (float*)carve((size_t)128 * NCH * 64 * 4);
  bf16* xr  = (bf16*)carve((size_t)TBTOK * CDIM * 2);
  bf16* xk  = (bf16*)carve((size_t)TBTOK * CDIM * 2);
  bf16* xv  = (bf16*)carve((size_t)TBTOK * CDIM * 2);
  bf16* xbf = (bf16*)carve((size_t)TBTOK * CDIM * 2);
  bf16* kv2b = xv;  // 32MB bf16 states, xv dead after rkv launch

  // 1. mixcvt + all weight prep
  prep_kern<<<dim3(8192 + 4545), 256, 0, stream>>>(
      x, x_r, x_k, x_v, xr, xk, xv, xbf,
      Wr, Wk, Wv, Wo, w1, a1, g1, x_w, x_a, x_g, g2, w2, a2,
      WrT, WkT, WvT, WoT, Bcat, g2T, w2T, a2T, zpad);
  // 2. rkv projections + LoRA stage1/stage2 (stage1 blocks dispatch first)
  rkv_stage1_kern<<<dim3(TBTOK / 128, 28), 256, 0, stream>>>(
      xr, xk, xv, WrT, WkT, WvT, r_buf, k_buf, v_buf,
      xbf, Bcat, zpad, w2T, a2T, w0, a0, t1g, w_arr, a_arr);
  // 3. WKV local scans (CHUNK=32; carry == prev chunk-final state)
  scan1_kern<<<dim3(128 * NCH / 4), 256, 0, stream>>>(
      k_buf, v_buf, r_buf, k_k, r_k, a_arr, w_arr, kv2b, Parr, bonus, Lend);
  // 4. gate GEMM + vectorized fixup/groupnorm/gating -> an (into r_buf)
  gate_post_kern<<<dim3(8, TBTOK / 128), 256, 0, stream>>>(
      t1g, g2T, kv2b, Parr, Lend, bonus, r_buf, v_buf, ln_w, ln_b);
  // 5. out = an @ Wo  (f32 output)
  gemm_wo_kern<<<dim3(TBTOK / 128, 8), 256, 0, stream>>>(r_buf, WoT, out);
}